// Round 1
// baseline (6812.474 us; speedup 1.0000x reference)
//
#include <hip/hip_runtime.h>
#include <math.h>

#define EPS 1e-8f

// ---------------- generic [R][C] -> [C][R] transpose (64x64 LDS tiles) ----------------
__global__ __launch_bounds__(256) void transpose_k(const float* __restrict__ in,
                                                   float* __restrict__ out, int R, int C) {
    __shared__ float tile[64][65];
    int tx = threadIdx.x & 63, ty = threadIdx.x >> 6;
    int c0 = blockIdx.x * 64, r0 = blockIdx.y * 64;
#pragma unroll
    for (int i = 0; i < 16; ++i) {
        int r = r0 + ty + i * 4, c = c0 + tx;
        if (r < R && c < C) tile[ty + i * 4][tx] = in[(long)r * C + c];
    }
    __syncthreads();
#pragma unroll
    for (int i = 0; i < 16; ++i) {
        int r = c0 + ty + i * 4, c = r0 + tx;
        if (r < C && c < R) out[(long)r * R + c] = tile[tx][ty + i * 4];
    }
}

// ---------------- conv1 9x9 stride1 + bias + relu : [256,1,28,28] -> [256,256,20,20] ----
// block = one image, 256 threads. thread: 4 channels x (5 rows x 2 half-rows of 10).
__global__ __launch_bounds__(256) void conv1_k(const float* __restrict__ x,
                                               const float* __restrict__ wt1,  // [81][256]
                                               const float* __restrict__ bias,
                                               float* __restrict__ h) {
    __shared__ float img[784];
    __shared__ float wl[81 * 256];
    int t = threadIdx.x, b = blockIdx.x;
    for (int i = t; i < 784; i += 256) img[i] = x[b * 784 + i];
    for (int i = t; i < 81 * 256; i += 256) wl[i] = wt1[i];
    __syncthreads();
    int lane = t & 63, grp = t >> 6;
    int co = lane * 4;
    float4 cb = *(const float4*)&bias[co];
    float bb[4] = {cb.x, cb.y, cb.z, cb.w};
    for (int oh = grp * 5; oh < grp * 5 + 5; ++oh) {
        for (int half = 0; half < 2; ++half) {
            int ow0 = half * 10;
            float acc[4][10];
#pragma unroll
            for (int cc = 0; cc < 4; ++cc)
#pragma unroll
                for (int p = 0; p < 10; ++p) acc[cc][p] = 0.f;
            for (int kh = 0; kh < 9; ++kh) {
                for (int kw = 0; kw < 9; ++kw) {
                    float4 w4 = *(const float4*)&wl[(kh * 9 + kw) * 256 + co];
                    const float* irow = &img[(oh + kh) * 28 + ow0 + kw];
#pragma unroll
                    for (int p = 0; p < 10; ++p) {
                        float iv = irow[p];
                        acc[0][p] += iv * w4.x;
                        acc[1][p] += iv * w4.y;
                        acc[2][p] += iv * w4.z;
                        acc[3][p] += iv * w4.w;
                    }
                }
            }
#pragma unroll
            for (int cc = 0; cc < 4; ++cc)
#pragma unroll
                for (int p = 0; p < 10; ++p)
                    h[b * 102400 + (co + cc) * 400 + oh * 20 + ow0 + p] =
                        fmaxf(acc[cc][p] + bb[cc], 0.f);
        }
    }
}

// ------------- primary caps conv 9x9 stride2 + bias, fused squash -> u [256,1152,8] -----
// block = one image, 256 threads. thread: 4 co x 9 positions (3x3 tile of the 6x6 output).
__global__ __launch_bounds__(256) void prim_k(const float* __restrict__ h,
                                              const float* __restrict__ wtp,  // [ci][81][256]
                                              const float* __restrict__ bias,
                                              float* __restrict__ u) {
    __shared__ float img[400];
    __shared__ float pl[9216];
    int t = threadIdx.x, b = blockIdx.x;
    int lane = t & 63, grp = t >> 6;
    int co = lane * 4;
    int gy = grp >> 1, gx = grp & 1;
    float acc[4][9];
#pragma unroll
    for (int cc = 0; cc < 4; ++cc)
#pragma unroll
        for (int p = 0; p < 9; ++p) acc[cc][p] = 0.f;

    for (int ci = 0; ci < 256; ++ci) {
        __syncthreads();
        for (int i = t; i < 400; i += 256) img[i] = h[b * 102400 + ci * 400 + i];
        __syncthreads();
        for (int kh = 0; kh < 9; ++kh) {
            for (int kw = 0; kw < 9; ++kw) {
                float4 w4 = *(const float4*)&wtp[(ci * 81 + kh * 9 + kw) * 256 + co];
#pragma unroll
                for (int p = 0; p < 9; ++p) {
                    int py = gy * 3 + p / 3, px = gx * 3 + p % 3;
                    float iv = img[(2 * py + kh) * 20 + 2 * px + kw];
                    acc[0][p] += iv * w4.x;
                    acc[1][p] += iv * w4.y;
                    acc[2][p] += iv * w4.z;
                    acc[3][p] += iv * w4.w;
                }
            }
        }
    }
    float4 pb4 = *(const float4*)&bias[co];
    float pb[4] = {pb4.x, pb4.y, pb4.z, pb4.w};
    __syncthreads();
#pragma unroll
    for (int cc = 0; cc < 4; ++cc)
#pragma unroll
        for (int p = 0; p < 9; ++p) {
            int py = gy * 3 + p / 3, px = gx * 3 + p % 3;
            pl[(co + cc) * 36 + py * 6 + px] = acc[cc][p] + pb[cc];
        }
    __syncthreads();
    // squash groups of 8 consecutive (flattened) elements
    for (int cap = t; cap < 1152; cap += 256) {
        float xs[8];
        float sn = 0.f;
#pragma unroll
        for (int d = 0; d < 8; ++d) {
            xs[d] = pl[cap * 8 + d];
            sn += xs[d] * xs[d];
        }
        float sc = sn / ((sn + 1.f) * (sqrtf(sn) + EPS));
#pragma unroll
        for (int d = 0; d < 8; ++d) u[b * 9216 + cap * 8 + d] = xs[d] * sc;
    }
}

// -------------- u_hat + 3-iter dynamic routing, one block per (c,b) --------------------
// b_logits(iter k) == u_hat * (v1+..+vk) broadcast over n => only vsum[e] scalars needed.
__global__ __launch_bounds__(256) void route_k(const float* __restrict__ u,
                                               const float* __restrict__ W,  // [10][1152][8][16]
                                               float* __restrict__ v) {
    __shared__ float uhl[16][1153];  // [e][n], pad to kill bank conflicts
    __shared__ float red[16][16];
    __shared__ float sE[16];
    int t = threadIdx.x;
    int c = blockIdx.x >> 8, b = blockIdx.x & 255;
    int e = t & 15, chunk = t >> 4;  // 16 chunks x 72 n each
    const float* Wc = W + c * 147456;
    const float* ub = u + b * 9216;
    for (int i = 0; i < 72; ++i) {
        int n = chunk * 72 + i;
        const float* un = ub + n * 8;
        const float* wn = Wc + n * 128 + e;
        float s = 0.f;
#pragma unroll
        for (int d = 0; d < 8; ++d) s += un[d] * wn[d * 16];
        uhl[e][n] = s;
    }
    __syncthreads();
    float vsum = 0.f, vlast = 0.f;
    for (int iter = 0; iter < 3; ++iter) {
        float mx = -1e30f;
        for (int i = 0; i < 72; ++i) mx = fmaxf(mx, uhl[e][chunk * 72 + i] * vsum);
        red[e][chunk] = mx;
        __syncthreads();
        float M = -1e30f;
#pragma unroll
        for (int k = 0; k < 16; ++k) M = fmaxf(M, red[e][k]);
        __syncthreads();
        float pe = 0.f, se = 0.f;
        for (int i = 0; i < 72; ++i) {
            float uv = uhl[e][chunk * 72 + i];
            float E = __expf(uv * vsum - M);
            pe += E;
            se += E * uv;
        }
        red[e][chunk] = pe;
        __syncthreads();
        float P = 0.f;
#pragma unroll
        for (int k = 0; k < 16; ++k) P += red[e][k];
        __syncthreads();
        red[e][chunk] = se;
        __syncthreads();
        float S = 0.f;
#pragma unroll
        for (int k = 0; k < 16; ++k) S += red[e][k];
        float sval = S / P;
        if (chunk == 0) sE[e] = sval;
        __syncthreads();
        float nrm = 0.f;
#pragma unroll
        for (int k = 0; k < 16; ++k) nrm += sE[k] * sE[k];
        float sc = nrm / ((nrm + 1.f) * (sqrtf(nrm) + EPS));
        vlast = sval * sc;
        vsum += vlast;
        __syncthreads();
    }
    if (chunk == 0) v[(b * 10 + c) * 16 + e] = vlast;
}

// -------------- logits = softmax over c of ||v|| ---------------------------------------
__global__ __launch_bounds__(256) void logits_k(const float* __restrict__ v,
                                                float* __restrict__ out) {
    int b = threadIdx.x;  // grid = 1 block of 256
    float nr[10];
#pragma unroll
    for (int c = 0; c < 10; ++c) {
        float s2 = 0.f;
#pragma unroll
        for (int e = 0; e < 16; ++e) {
            float xv = v[(b * 10 + c) * 16 + e];
            s2 += xv * xv;
        }
        nr[c] = sqrtf(s2);
    }
    float mx = nr[0];
#pragma unroll
    for (int c = 1; c < 10; ++c) mx = fmaxf(mx, nr[c]);
    float ex[10], sm = 0.f;
#pragma unroll
    for (int c = 0; c < 10; ++c) {
        ex[c] = __expf(nr[c] - mx);
        sm += ex[c];
    }
#pragma unroll
    for (int c = 0; c < 10; ++c) out[b * 10 + c] = ex[c] / sm;
}

// -------------- fc1: picks the 16 columns selected by y ------------------------------
__global__ __launch_bounds__(256) void fc1_k(const float* __restrict__ v,
                                             const int* __restrict__ y,
                                             const float* __restrict__ w1,
                                             const float* __restrict__ b1,
                                             float* __restrict__ h1) {
    int b = blockIdx.x, t = threadIdx.x;
    __shared__ float vs[16];
    int cls = y[b];
    if (t < 16) vs[t] = v[(b * 10 + cls) * 16 + t];
    __syncthreads();
    for (int j = t; j < 512; j += 256) {
        float a = b1[j];
#pragma unroll
        for (int d = 0; d < 16; ++d) a += vs[d] * w1[(cls * 16 + d) * 512 + j];
        h1[b * 512 + j] = fmaxf(a, 0.f);
    }
}

// -------------- generic fc: C[256,N] = (relu?)(A[256,K] @ W[K,N] + bias) ---------------
// grid (ceil(N/256), 16); 16 rows of A staged in LDS per block.
__global__ __launch_bounds__(256) void fc_k(const float* __restrict__ A,
                                            const float* __restrict__ Wt,
                                            const float* __restrict__ bias,
                                            float* __restrict__ C,
                                            int K, int N, int relu) {
    __shared__ float al[16 * 1024];
    int t = threadIdx.x;
    int j = blockIdx.x * 256 + t;
    int r0 = blockIdx.y * 16;
    for (int idx = t; idx < 16 * K; idx += 256) {
        int r = idx / K, kk = idx - r * K;
        al[r * K + kk] = A[(r0 + r) * K + kk];
    }
    __syncthreads();
    if (j < N) {
        float bj = bias[j];
        float acc[16];
#pragma unroll
        for (int i = 0; i < 16; ++i) acc[i] = bj;
        for (int k = 0; k < K; ++k) {
            float w = Wt[(long)k * N + j];
#pragma unroll
            for (int i = 0; i < 16; ++i) acc[i] += al[i * K + k] * w;
        }
#pragma unroll
        for (int i = 0; i < 16; ++i) {
            float o = acc[i];
            if (relu) o = fmaxf(o, 0.f);
            C[(r0 + i) * N + j] = o;
        }
    }
}

extern "C" void kernel_launch(void* const* d_in, const int* in_sizes, int n_in,
                              void* d_out, int out_size, void* d_ws, size_t ws_size,
                              hipStream_t stream) {
    (void)in_sizes; (void)n_in; (void)out_size; (void)ws_size;
    const float* x       = (const float*)d_in[0];
    const int*   y       = (const int*)d_in[1];
    const float* conv1_w = (const float*)d_in[2];
    const float* conv1_b = (const float*)d_in[3];
    const float* prim_w  = (const float*)d_in[4];
    const float* prim_b  = (const float*)d_in[5];
    const float* route_W = (const float*)d_in[6];
    const float* dec_w1  = (const float*)d_in[7];
    const float* dec_b1  = (const float*)d_in[8];
    const float* dec_w2  = (const float*)d_in[9];
    const float* dec_b2  = (const float*)d_in[10];
    const float* dec_w3  = (const float*)d_in[11];
    const float* dec_b3  = (const float*)d_in[12];
    float* out = (float*)d_out;

    float* ws  = (float*)d_ws;
    float* h   = ws;               // 256*256*400       = 26214400
    float* wtp = h + 26214400;     // 20736*256         = 5308416
    float* wt1 = wtp + 5308416;    // 81*256            = 20736
    float* u   = wt1 + 20736;      // 256*1152*8        = 2359296
    float* v   = u + 2359296;      // 256*10*16         = 40960
    float* h1  = v + 40960;        // 256*512           = 131072
    float* h2  = h1 + 131072;      // 256*1024          = 262144

    hipLaunchKernelGGL(transpose_k, dim3(2, 4), dim3(256), 0, stream, conv1_w, wt1, 256, 81);
    hipLaunchKernelGGL(transpose_k, dim3(324, 4), dim3(256), 0, stream, prim_w, wtp, 256, 20736);
    hipLaunchKernelGGL(conv1_k, dim3(256), dim3(256), 0, stream, x, wt1, conv1_b, h);
    hipLaunchKernelGGL(prim_k, dim3(256), dim3(256), 0, stream, h, wtp, prim_b, u);
    hipLaunchKernelGGL(route_k, dim3(2560), dim3(256), 0, stream, u, route_W, v);
    hipLaunchKernelGGL(logits_k, dim3(1), dim3(256), 0, stream, v, out);
    hipLaunchKernelGGL(fc1_k, dim3(256), dim3(256), 0, stream, v, y, dec_w1, dec_b1, h1);
    hipLaunchKernelGGL(fc_k, dim3(4, 16), dim3(256), 0, stream, h1, dec_w2, dec_b2, h2, 512, 1024, 1);
    hipLaunchKernelGGL(fc_k, dim3(4, 16), dim3(256), 0, stream, h2, dec_w3, dec_b3, out + 2560, 1024, 784, 0);
}

// Round 2
// 1495.178 us; speedup vs baseline: 4.5563x; 4.5563x over previous
//
#include <hip/hip_runtime.h>
#include <hip/hip_fp16.h>
#include <math.h>

#define EPS 1e-8f

typedef _Float16 f16x8 __attribute__((ext_vector_type(8)));
typedef float f32x4 __attribute__((ext_vector_type(4)));

// ---------------- generic [R][C] -> [C][R] transpose (64x64 LDS tiles) ----------------
__global__ __launch_bounds__(256) void transpose_k(const float* __restrict__ in,
                                                   float* __restrict__ out, int R, int C) {
    __shared__ float tile[64][65];
    int tx = threadIdx.x & 63, ty = threadIdx.x >> 6;
    int c0 = blockIdx.x * 64, r0 = blockIdx.y * 64;
#pragma unroll
    for (int i = 0; i < 16; ++i) {
        int r = r0 + ty + i * 4, c = c0 + tx;
        if (r < R && c < C) tile[ty + i * 4][tx] = in[(long)r * C + c];
    }
    __syncthreads();
#pragma unroll
    for (int i = 0; i < 16; ++i) {
        int r = c0 + ty + i * 4, c = r0 + tx;
        if (r < C && c < R) out[(long)r * R + c] = tile[tx][ty + i * 4];
    }
}

// -------- weight prep: prim_w [co][ci][81] f32 -> w2h/w2l [co][tap][ci] fp16 hi/lo ------
// block = (co, ci-half). LDS stages [128 ci][81 tap] plane slice.
__global__ __launch_bounds__(256) void wprep_k(const float* __restrict__ prim_w,
                                               __half* __restrict__ w2h,
                                               __half* __restrict__ w2l) {
    __shared__ float pl[128 * 81];
    int t = threadIdx.x, co = blockIdx.x, cih = blockIdx.y;
    for (int i = t; i < 10368; i += 256) pl[i] = prim_w[co * 20736 + cih * 10368 + i];
    __syncthreads();
    for (int o = t; o < 10368; o += 256) {  // o = tap*128 + cil
        int tap = o >> 7, cil = o & 127;
        float v = pl[cil * 81 + tap];
        __half hi = __float2half(v);
        __half lo = __float2half(v - __half2float(hi));
        long oo = (long)co * 20736 + tap * 256 + cih * 128 + cil;
        w2h[oo] = hi;
        w2l[oo] = lo;
    }
}

// ---------------- conv1 9x9 stride1 + bias + relu -> hh [b][400 pix][256 ci] fp16 -------
// grid (256 images, 2 co-halves). thread: 2 co x (5 rows x 2 half-rows of 10).
__global__ __launch_bounds__(256) void conv1_k(const float* __restrict__ x,
                                               const float* __restrict__ wt1,  // [81][256]
                                               const float* __restrict__ bias,
                                               __half* __restrict__ hh) {
    __shared__ float img[784];
    __shared__ float wl2[81 * 128];
    int t = threadIdx.x, b = blockIdx.x, chalf = blockIdx.y;
    for (int i = t; i < 784; i += 256) img[i] = x[b * 784 + i];
    for (int i = t; i < 81 * 128; i += 256) {
        int tap = i >> 7, j = i & 127;
        wl2[i] = wt1[tap * 256 + chalf * 128 + j];
    }
    __syncthreads();
    int lane = t & 63, grp = t >> 6;
    int col = lane * 2;  // co within half
    float2 cb = *(const float2*)&bias[chalf * 128 + col];
    for (int oh = grp * 5; oh < grp * 5 + 5; ++oh) {
        for (int hf = 0; hf < 2; ++hf) {
            int ow0 = hf * 10;
            float acc0[10], acc1[10];
#pragma unroll
            for (int p = 0; p < 10; ++p) { acc0[p] = 0.f; acc1[p] = 0.f; }
            for (int kh = 0; kh < 9; ++kh) {
                for (int kw = 0; kw < 9; ++kw) {
                    float2 w2 = *(const float2*)&wl2[(kh * 9 + kw) * 128 + col];
                    const float* irow = &img[(oh + kh) * 28 + ow0 + kw];
#pragma unroll
                    for (int p = 0; p < 10; ++p) {
                        float iv = irow[p];
                        acc0[p] += iv * w2.x;
                        acc1[p] += iv * w2.y;
                    }
                }
            }
#pragma unroll
            for (int p = 0; p < 10; ++p) {
                int pix = oh * 20 + ow0 + p;
                float v0 = fmaxf(acc0[p] + cb.x, 0.f);
                float v1 = fmaxf(acc1[p] + cb.y, 0.f);
                __half2 hv;
                hv.x = __float2half(v0);
                hv.y = __float2half(v1);
                *(__half2*)&hh[((long)b * 400 + pix) * 256 + chalf * 128 + col] = hv;
            }
        }
    }
}

// ---------------- primary-caps implicit GEMM via MFMA --------------------------------
// C[m=(b,oy,ox)][co] = sum_{tap,ci} hh[b][pix(m,tap)][ci] * W[co][tap][ci]
// A-op = W tile [64 co][32 ci], B-op = patches [144 m][32 ci]; 2-pass fp16 hi/lo on W.
// grid (64 m-tiles, 4 co-tiles), 256 threads = 4 waves; wave w -> co-frag w, 9 m-frags.
__global__ __launch_bounds__(256) void primgemm_k(const __half* __restrict__ hh,
                                                  const __half* __restrict__ w2h,
                                                  const __half* __restrict__ w2l,
                                                  float* __restrict__ Cp) {
    // per-buffer layout: Wh [0,4096), Wl [4096,8192), P [8192,17408)
    __shared__ __align__(16) char lds[2][17408];
    const int t = threadIdx.x;
    const int mb = blockIdx.x;  // 0..63
    const int cb = blockIdx.y;  // 0..3
    const int lane = t & 63;
    const int w = t >> 6;
    const int l15 = lane & 15, kl = lane >> 4;

    // --- fixed per-thread staging geometry ---
    const int wrow = t >> 2, wch = t & 3;  // W slot: 64 rows x 4 chunks
    const long wbase = (long)(cb * 64 + wrow) * (81 * 256) + wch * 8;
    const int wlofs = wrow * 64 + (((wch ^ ((wrow >> 1) & 3))) << 4);
    int npslots = (t < 64) ? 3 : 2;  // P: 144 rows x 4 chunks = 576 slots
    long pbase[3];
    int plofs[3];
#pragma unroll
    for (int k = 0; k < 3; ++k) {
        int s = t + 256 * k;
        if (s >= 576) s = 0;  // dummy (masked by npslots)
        int r = s >> 2, ch = s & 3;
        int m = mb * 144 + r;
        int bi = m / 36, pos = m - bi * 36;
        int oy = pos / 6, ox = pos - oy * 6;
        pbase[k] = ((long)bi * 400 + (oy * 40 + ox * 2)) * 256 + ch * 8;
        plofs[k] = 8192 + r * 64 + (((ch ^ ((r >> 1) & 3))) << 4);
    }

    f32x4 acc[9];
#pragma unroll
    for (int i = 0; i < 9; ++i) acc[i] = (f32x4){0.f, 0.f, 0.f, 0.f};

    float4 rWh, rWl, rP[3];

    // chunk c: tap = c>>3, cic = c&7  (32 ci per chunk)
    auto loadRegs = [&](int c) {
        int tap = c >> 3, cic = c & 7;
        int kh = tap / 9, kw = tap - kh * 9;
        long wofs = wbase + tap * 256 + cic * 32;
        rWh = *(const float4*)(w2h + wofs);
        rWl = *(const float4*)(w2l + wofs);
        long pixofs = (long)(kh * 20 + kw) * 256 + cic * 32;
        for (int k = 0; k < npslots; ++k)
            rP[k] = *(const float4*)(hh + pbase[k] + pixofs);
    };
    auto writeLds = [&](int buf) {
        char* B = lds[buf];
        *(float4*)(B + wlofs) = rWh;
        *(float4*)(B + 4096 + wlofs) = rWl;
        for (int k = 0; k < npslots; ++k) *(float4*)(B + plofs[k]) = rP[k];
    };

    const int arow = w * 16 + l15;
    const int aofs = arow * 64 + ((kl ^ ((arow >> 1) & 3)) << 4);

    loadRegs(0);
    writeLds(0);
    for (int c = 0; c < 648; ++c) {
        if (c + 1 < 648) loadRegs(c + 1);
        __syncthreads();
        const char* Bf = lds[c & 1];
        f16x8 ah = *(const f16x8*)(Bf + aofs);
        f16x8 al = *(const f16x8*)(Bf + 4096 + aofs);
#pragma unroll
        for (int mf = 0; mf < 9; ++mf) {
            int pr = mf * 16 + l15;
            int pofs = 8192 + pr * 64 + ((kl ^ ((pr >> 1) & 3)) << 4);
            f16x8 bp = *(const f16x8*)(Bf + pofs);
            acc[mf] = __builtin_amdgcn_mfma_f32_16x16x32_f16(ah, bp, acc[mf], 0, 0, 0);
            acc[mf] = __builtin_amdgcn_mfma_f32_16x16x32_f16(al, bp, acc[mf], 0, 0, 0);
        }
        if (c + 1 < 648) writeLds((c + 1) & 1);
    }

    // epilogue: D col = m (lane&15), row = co ((lane>>4)*4 + j)
#pragma unroll
    for (int mf = 0; mf < 9; ++mf) {
        int m = mb * 144 + mf * 16 + l15;
        int co0 = cb * 64 + w * 16 + kl * 4;
        *(float4*)(Cp + (long)m * 256 + co0) = *(float4*)&acc[mf];
    }
}

// -------------- bias + capsule regroup + squash -> u [b][1152][8] f32 ------------------
__global__ __launch_bounds__(256) void squashp_k(const float* __restrict__ Cp,
                                                 const float* __restrict__ bias,
                                                 float* __restrict__ u) {
    __shared__ float sm[9216];  // [pos][co]
    __shared__ float bs[256];
    int t = threadIdx.x, b = blockIdx.x;
    bs[t] = bias[t];
    for (int i = t; i < 9216; i += 256) sm[i] = Cp[(long)b * 9216 + i];
    __syncthreads();
    for (int cap = t; cap < 1152; cap += 256) {
        float xs[8], sn = 0.f;
#pragma unroll
        for (int d = 0; d < 8; ++d) {
            int f = cap * 8 + d;
            int co = f / 36, pos = f - co * 36;
            float vv = sm[pos * 256 + co] + bs[co];
            xs[d] = vv;
            sn += vv * vv;
        }
        float sc = sn / ((sn + 1.f) * (sqrtf(sn) + EPS));
#pragma unroll
        for (int d = 0; d < 8; ++d) u[(long)b * 9216 + cap * 8 + d] = xs[d] * sc;
    }
}

// -------------- u_hat + 3-iter dynamic routing, one block per (c,b) --------------------
__global__ __launch_bounds__(256) void route_k(const float* __restrict__ u,
                                               const float* __restrict__ W,  // [10][1152][8][16]
                                               float* __restrict__ v) {
    __shared__ float uhl[16][1153];
    __shared__ float red[16][16];
    __shared__ float sE[16];
    int t = threadIdx.x;
    int c = blockIdx.x >> 8, b = blockIdx.x & 255;
    int e = t & 15, chunk = t >> 4;
    const float* Wc = W + c * 147456;
    const float* ub = u + b * 9216;
    for (int i = 0; i < 72; ++i) {
        int n = chunk * 72 + i;
        const float* un = ub + n * 8;
        const float* wn = Wc + n * 128 + e;
        float s = 0.f;
#pragma unroll
        for (int d = 0; d < 8; ++d) s += un[d] * wn[d * 16];
        uhl[e][n] = s;
    }
    __syncthreads();
    float vsum = 0.f, vlast = 0.f;
    for (int iter = 0; iter < 3; ++iter) {
        float mx = -1e30f;
        for (int i = 0; i < 72; ++i) mx = fmaxf(mx, uhl[e][chunk * 72 + i] * vsum);
        red[e][chunk] = mx;
        __syncthreads();
        float M = -1e30f;
#pragma unroll
        for (int k = 0; k < 16; ++k) M = fmaxf(M, red[e][k]);
        __syncthreads();
        float pe = 0.f, se = 0.f;
        for (int i = 0; i < 72; ++i) {
            float uv = uhl[e][chunk * 72 + i];
            float E = __expf(uv * vsum - M);
            pe += E;
            se += E * uv;
        }
        red[e][chunk] = pe;
        __syncthreads();
        float P = 0.f;
#pragma unroll
        for (int k = 0; k < 16; ++k) P += red[e][k];
        __syncthreads();
        red[e][chunk] = se;
        __syncthreads();
        float S = 0.f;
#pragma unroll
        for (int k = 0; k < 16; ++k) S += red[e][k];
        float sval = S / P;
        if (chunk == 0) sE[e] = sval;
        __syncthreads();
        float nrm = 0.f;
#pragma unroll
        for (int k = 0; k < 16; ++k) nrm += sE[k] * sE[k];
        float sc = nrm / ((nrm + 1.f) * (sqrtf(nrm) + EPS));
        vlast = sval * sc;
        vsum += vlast;
        __syncthreads();
    }
    if (chunk == 0) v[(b * 10 + c) * 16 + e] = vlast;
}

// -------------- logits = softmax over c of ||v|| ---------------------------------------
__global__ __launch_bounds__(256) void logits_k(const float* __restrict__ v,
                                                float* __restrict__ out) {
    int b = threadIdx.x;
    float nr[10];
#pragma unroll
    for (int c = 0; c < 10; ++c) {
        float s2 = 0.f;
#pragma unroll
        for (int e = 0; e < 16; ++e) {
            float xv = v[(b * 10 + c) * 16 + e];
            s2 += xv * xv;
        }
        nr[c] = sqrtf(s2);
    }
    float mx = nr[0];
#pragma unroll
    for (int c = 1; c < 10; ++c) mx = fmaxf(mx, nr[c]);
    float ex[10], sm = 0.f;
#pragma unroll
    for (int c = 0; c < 10; ++c) {
        ex[c] = __expf(nr[c] - mx);
        sm += ex[c];
    }
#pragma unroll
    for (int c = 0; c < 10; ++c) out[b * 10 + c] = ex[c] / sm;
}

// -------------- fc1: picks the 16 columns selected by y ------------------------------
__global__ __launch_bounds__(256) void fc1_k(const float* __restrict__ v,
                                             const int* __restrict__ y,
                                             const float* __restrict__ w1,
                                             const float* __restrict__ b1,
                                             float* __restrict__ h1) {
    int b = blockIdx.x, t = threadIdx.x;
    __shared__ float vs[16];
    int cls = y[b];
    if (t < 16) vs[t] = v[(b * 10 + cls) * 16 + t];
    __syncthreads();
    for (int j = t; j < 512; j += 256) {
        float a = b1[j];
#pragma unroll
        for (int d = 0; d < 16; ++d) a += vs[d] * w1[(cls * 16 + d) * 512 + j];
        h1[b * 512 + j] = fmaxf(a, 0.f);
    }
}

// -------------- generic fc: C[256,N] = (relu?)(A[256,K] @ W[K,N] + bias) ---------------
__global__ __launch_bounds__(256) void fc_k(const float* __restrict__ A,
                                            const float* __restrict__ Wt,
                                            const float* __restrict__ bias,
                                            float* __restrict__ C,
                                            int K, int N, int relu) {
    __shared__ float al[16 * 1024];
    int t = threadIdx.x;
    int j = blockIdx.x * 256 + t;
    int r0 = blockIdx.y * 16;
    for (int idx = t; idx < 16 * K; idx += 256) {
        int r = idx / K, kk = idx - r * K;
        al[r * K + kk] = A[(r0 + r) * K + kk];
    }
    __syncthreads();
    if (j < N) {
        float bj = bias[j];
        float acc[16];
#pragma unroll
        for (int i = 0; i < 16; ++i) acc[i] = bj;
        for (int k = 0; k < K; ++k) {
            float w = Wt[(long)k * N + j];
#pragma unroll
            for (int i = 0; i < 16; ++i) acc[i] += al[i * K + k] * w;
        }
#pragma unroll
        for (int i = 0; i < 16; ++i) {
            float o = acc[i];
            if (relu) o = fmaxf(o, 0.f);
            C[(r0 + i) * N + j] = o;
        }
    }
}

extern "C" void kernel_launch(void* const* d_in, const int* in_sizes, int n_in,
                              void* d_out, int out_size, void* d_ws, size_t ws_size,
                              hipStream_t stream) {
    (void)in_sizes; (void)n_in; (void)out_size; (void)ws_size;
    const float* x       = (const float*)d_in[0];
    const int*   y       = (const int*)d_in[1];
    const float* conv1_w = (const float*)d_in[2];
    const float* conv1_b = (const float*)d_in[3];
    const float* prim_w  = (const float*)d_in[4];
    const float* prim_b  = (const float*)d_in[5];
    const float* route_W = (const float*)d_in[6];
    const float* dec_w1  = (const float*)d_in[7];
    const float* dec_b1  = (const float*)d_in[8];
    const float* dec_w2  = (const float*)d_in[9];
    const float* dec_b2  = (const float*)d_in[10];
    const float* dec_w3  = (const float*)d_in[11];
    const float* dec_b3  = (const float*)d_in[12];
    float* out = (float*)d_out;

    float* ws  = (float*)d_ws;
    float* Cp  = ws;                  // 2359296 f32
    float* u   = Cp + 2359296;        // 2359296 f32
    float* wt1 = u + 2359296;         // 20736 f32
    float* v   = wt1 + 20736;         // 40960 f32
    float* h1  = v + 40960;           // 131072 f32
    float* h2  = h1 + 131072;         // 262144 f32
    __half* hh  = (__half*)(h2 + 262144);  // 26214400 halfs
    __half* w2h = hh + 26214400;           // 5308416 halfs
    __half* w2l = w2h + 5308416;           // 5308416 halfs

    hipLaunchKernelGGL(transpose_k, dim3(2, 4), dim3(256), 0, stream, conv1_w, wt1, 256, 81);
    hipLaunchKernelGGL(wprep_k, dim3(256, 2), dim3(256), 0, stream, prim_w, w2h, w2l);
    hipLaunchKernelGGL(conv1_k, dim3(256, 2), dim3(256), 0, stream, x, wt1, conv1_b, hh);
    hipLaunchKernelGGL(primgemm_k, dim3(64, 4), dim3(256), 0, stream, hh, w2h, w2l, Cp);
    hipLaunchKernelGGL(squashp_k, dim3(256), dim3(256), 0, stream, Cp, prim_b, u);
    hipLaunchKernelGGL(route_k, dim3(2560), dim3(256), 0, stream, u, route_W, v);
    hipLaunchKernelGGL(logits_k, dim3(1), dim3(256), 0, stream, v, out);
    hipLaunchKernelGGL(fc1_k, dim3(256), dim3(256), 0, stream, v, y, dec_w1, dec_b1, h1);
    hipLaunchKernelGGL(fc_k, dim3(4, 16), dim3(256), 0, stream, h1, dec_w2, dec_b2, h2, 512, 1024, 1);
    hipLaunchKernelGGL(fc_k, dim3(4, 16), dim3(256), 0, stream, h2, dec_w3, dec_b3, out + 2560, 1024, 784, 0);
}

// Round 3
// 760.424 us; speedup vs baseline: 8.9588x; 1.9662x over previous
//
#include <hip/hip_runtime.h>
#include <hip/hip_fp16.h>
#include <math.h>

#define EPS 1e-8f
#define AS1 __attribute__((address_space(1)))
#define AS3 __attribute__((address_space(3)))

typedef _Float16 f16x8 __attribute__((ext_vector_type(8)));
typedef float f32x4 __attribute__((ext_vector_type(4)));

// ---------------- generic [R][C] -> [C][R] transpose (64x64 LDS tiles) ----------------
__global__ __launch_bounds__(256) void transpose_k(const float* __restrict__ in,
                                                   float* __restrict__ out, int R, int C) {
    __shared__ float tile[64][65];
    int tx = threadIdx.x & 63, ty = threadIdx.x >> 6;
    int c0 = blockIdx.x * 64, r0 = blockIdx.y * 64;
#pragma unroll
    for (int i = 0; i < 16; ++i) {
        int r = r0 + ty + i * 4, c = c0 + tx;
        if (r < R && c < C) tile[ty + i * 4][tx] = in[(long)r * C + c];
    }
    __syncthreads();
#pragma unroll
    for (int i = 0; i < 16; ++i) {
        int r = c0 + ty + i * 4, c = r0 + tx;
        if (r < C && c < R) out[(long)r * R + c] = tile[tx][ty + i * 4];
    }
}

// -------- weight prep: prim_w [co][ci][81] f32 -> w2 [co][tap][ci] fp16 (single) --------
__global__ __launch_bounds__(256) void wprep_k(const float* __restrict__ prim_w,
                                               __half* __restrict__ w2) {
    __shared__ float pl[128 * 81];
    int t = threadIdx.x, co = blockIdx.x, cih = blockIdx.y;
    for (int i = t; i < 10368; i += 256) pl[i] = prim_w[co * 20736 + cih * 10368 + i];
    __syncthreads();
    for (int o = t; o < 10368; o += 256) {  // o = tap*128 + cil
        int tap = o >> 7, cil = o & 127;
        w2[(long)co * 20736 + tap * 256 + cih * 128 + cil] = __float2half(pl[cil * 81 + tap]);
    }
}

// ---------------- conv1 9x9 stride1 + bias + relu -> hh [b][400 pix][256 ci] fp16 -------
__global__ __launch_bounds__(256) void conv1_k(const float* __restrict__ x,
                                               const float* __restrict__ wt1,  // [81][256]
                                               const float* __restrict__ bias,
                                               __half* __restrict__ hh) {
    __shared__ float img[784];
    __shared__ float wl2[81 * 128];
    int t = threadIdx.x, b = blockIdx.x, chalf = blockIdx.y;
    for (int i = t; i < 784; i += 256) img[i] = x[b * 784 + i];
    for (int i = t; i < 81 * 128; i += 256) {
        int tap = i >> 7, j = i & 127;
        wl2[i] = wt1[tap * 256 + chalf * 128 + j];
    }
    __syncthreads();
    int lane = t & 63, grp = t >> 6;
    int col = lane * 2;
    float2 cb = *(const float2*)&bias[chalf * 128 + col];
    for (int oh = grp * 5; oh < grp * 5 + 5; ++oh) {
        for (int hf = 0; hf < 2; ++hf) {
            int ow0 = hf * 10;
            float acc0[10], acc1[10];
#pragma unroll
            for (int p = 0; p < 10; ++p) { acc0[p] = 0.f; acc1[p] = 0.f; }
            for (int kh = 0; kh < 9; ++kh) {
                for (int kw = 0; kw < 9; ++kw) {
                    float2 w2v = *(const float2*)&wl2[(kh * 9 + kw) * 128 + col];
                    const float* irow = &img[(oh + kh) * 28 + ow0 + kw];
#pragma unroll
                    for (int p = 0; p < 10; ++p) {
                        float iv = irow[p];
                        acc0[p] += iv * w2v.x;
                        acc1[p] += iv * w2v.y;
                    }
                }
            }
#pragma unroll
            for (int p = 0; p < 10; ++p) {
                int pix = oh * 20 + ow0 + p;
                __half2 hv;
                hv.x = __float2half(fmaxf(acc0[p] + cb.x, 0.f));
                hv.y = __float2half(fmaxf(acc1[p] + cb.y, 0.f));
                *(__half2*)&hh[((long)b * 400 + pix) * 256 + chalf * 128 + col] = hv;
            }
        }
    }
}

// ---------------- primary-caps implicit GEMM v2 ----------------------------------------
// C[m=(b,oy,ox)][co] = sum_{tap,ci} hh[b][pix(m,tap)][ci] * W[co][tap][ci]
// BM=128, BN=128, BK=64, K split 4 ways (81 steps each). grid (144 mn-tiles, 4 kslices).
// 4 waves; wave w owns m-frags {w, w+4} x all 8 n-frags. A: global->reg direct.
// W: LDS double-buffered via global_load_lds, XOR-swizzled source + swizzled ds_read.
__global__ __launch_bounds__(256) void primgemm_k(const __half* __restrict__ hh,
                                                  const __half* __restrict__ w2,
                                                  float* __restrict__ Cpart) {
    __shared__ __align__(16) char wbuf[2][16384];  // [128 co][64 ci] halfs, swizzled
    const int t = threadIdx.x;
    const int lane = t & 63, w = t >> 6;
    const int l15 = lane & 15, kl = lane >> 4;

    // XCD-chunked bijective swizzle of the 144 mn-tiles (144 = 8*18), nb-major order
    int xr = blockIdx.x;
    int swz = (xr & 7) * 18 + (xr >> 3);
    const int nb = swz / 72, mt = swz - nb * 72;
    const int ks = blockIdx.y;
    const int kq0 = ks * 81;

    // A row bases (per-lane, fixed): m-frags {w, w+4}
    long abase[2];
    int mrow[2];
#pragma unroll
    for (int mf2 = 0; mf2 < 2; ++mf2) {
        int m = mt * 128 + (w + mf2 * 4) * 16 + l15;
        mrow[mf2] = m;
        int bi = m / 36, pos = m - bi * 36;
        int oy = pos / 6, ox = pos - oy * 6;
        abase[mf2] = ((long)bi * 400 + oy * 40 + ox * 2) * 256 + kl * 8;
    }

    // W stage source addrs (per-lane, fixed except per-step uniform offset)
    long wsrc[4];
    int ldsdst[4];
#pragma unroll
    for (int q = 0; q < 4; ++q) {
        int o = (w * 4 + q) * 1024 + lane * 16;  // phys byte in 16KB buffer
        int row = o >> 7;
        int pc = (o >> 4) & 7;
        int lc = pc ^ (row & 7);
        wsrc[q] = (long)(nb * 128 + row) * 20736 + lc * 8;
        ldsdst[q] = (w * 4 + q) * 1024;  // wave-uniform
    }

    f32x4 acc[2][8];
#pragma unroll
    for (int i = 0; i < 2; ++i)
#pragma unroll
        for (int j = 0; j < 8; ++j) acc[i][j] = (f32x4){0.f, 0.f, 0.f, 0.f};

    auto kdec = [](int kq, int& aoff, int& woff) {
        int tap = kq >> 2, cih = kq & 3;
        int kh = tap / 9, kw = tap - kh * 9;
        aoff = (kh * 20 + kw) * 256 + cih * 64;
        woff = tap * 256 + cih * 64;
    };
    auto stage = [&](int bufi, int woff) {
#pragma unroll
        for (int q = 0; q < 4; ++q) {
            __builtin_amdgcn_global_load_lds((const AS1 void*)(w2 + wsrc[q] + woff),
                                             (AS3 void*)(&wbuf[bufi][ldsdst[q]]), 16, 0, 0);
        }
    };

    int aoff, woff;
    kdec(kq0, aoff, woff);
    stage(0, woff);
    __syncthreads();
    int buf = 0;
    for (int s = 0; s < 81; ++s) {
        int aoffn = 0, woffn = 0;
        if (s + 1 < 81) {
            kdec(kq0 + s + 1, aoffn, woffn);
            stage(buf ^ 1, woffn);
        }
        // A fragments: direct global->reg
        f16x8 af[2][2];
#pragma unroll
        for (int mf2 = 0; mf2 < 2; ++mf2)
#pragma unroll
            for (int kk = 0; kk < 2; ++kk)
                af[mf2][kk] = *(const f16x8*)(hh + abase[mf2] + aoff + kk * 32);
        // W fragments from LDS + MFMA
        const char* WB = wbuf[buf];
#pragma unroll
        for (int nf = 0; nf < 8; ++nf) {
            int row0 = nf * 16 + l15;
            int rb = row0 * 128, sw = row0 & 7;
            f16x8 w0 = *(const f16x8*)(WB + rb + ((kl ^ sw) << 4));
            f16x8 w1 = *(const f16x8*)(WB + rb + (((4 + kl) ^ sw) << 4));
            acc[0][nf] = __builtin_amdgcn_mfma_f32_16x16x32_f16(w0, af[0][0], acc[0][nf], 0, 0, 0);
            acc[1][nf] = __builtin_amdgcn_mfma_f32_16x16x32_f16(w0, af[1][0], acc[1][nf], 0, 0, 0);
            acc[0][nf] = __builtin_amdgcn_mfma_f32_16x16x32_f16(w1, af[0][1], acc[0][nf], 0, 0, 0);
            acc[1][nf] = __builtin_amdgcn_mfma_f32_16x16x32_f16(w1, af[1][1], acc[1][nf], 0, 0, 0);
        }
        __syncthreads();
        buf ^= 1;
        aoff = aoffn;
        woff = woffn;
    }

    // epilogue: D col = m (lane&15), row = co ((lane>>4)*4 + j)
    float* Cp = Cpart + (long)ks * 2359296;
#pragma unroll
    for (int mf2 = 0; mf2 < 2; ++mf2)
#pragma unroll
        for (int nf = 0; nf < 8; ++nf) {
            int co = nb * 128 + nf * 16 + kl * 4;
            *(f32x4*)(Cp + (long)mrow[mf2] * 256 + co) = acc[mf2][nf];
        }
}

// -------------- sum 4 K-partials + bias + capsule regroup + squash -> u ----------------
__global__ __launch_bounds__(256) void squashp_k(const float* __restrict__ Cpart,
                                                 const float* __restrict__ bias,
                                                 float* __restrict__ u) {
    __shared__ float sm[9216];  // [pos][co]
    __shared__ float bs[256];
    int t = threadIdx.x, b = blockIdx.x;
    bs[t] = bias[t];
    for (int i = t; i < 9216; i += 256) {
        float s = 0.f;
#pragma unroll
        for (int ks = 0; ks < 4; ++ks) s += Cpart[(long)ks * 2359296 + (long)b * 9216 + i];
        sm[i] = s;
    }
    __syncthreads();
    for (int cap = t; cap < 1152; cap += 256) {
        float xs[8], sn = 0.f;
#pragma unroll
        for (int d = 0; d < 8; ++d) {
            int f = cap * 8 + d;
            int co = f / 36, pos = f - co * 36;
            float vv = sm[pos * 256 + co] + bs[co];
            xs[d] = vv;
            sn += vv * vv;
        }
        float sc = sn / ((sn + 1.f) * (sqrtf(sn) + EPS));
#pragma unroll
        for (int d = 0; d < 8; ++d) u[(long)b * 9216 + cap * 8 + d] = xs[d] * sc;
    }
}

// -------------- u_hat + 3-iter dynamic routing, one block per (c,b) --------------------
__global__ __launch_bounds__(256) void route_k(const float* __restrict__ u,
                                               const float* __restrict__ W,  // [10][1152][8][16]
                                               float* __restrict__ v) {
    __shared__ float uhl[16][1153];
    __shared__ float red[16][16];
    __shared__ float sE[16];
    int t = threadIdx.x;
    int c = blockIdx.x >> 8, b = blockIdx.x & 255;
    int e = t & 15, chunk = t >> 4;
    const float* Wc = W + c * 147456;
    const float* ub = u + b * 9216;
    for (int i = 0; i < 72; ++i) {
        int n = chunk * 72 + i;
        const float* un = ub + n * 8;
        const float* wn = Wc + n * 128 + e;
        float s = 0.f;
#pragma unroll
        for (int d = 0; d < 8; ++d) s += un[d] * wn[d * 16];
        uhl[e][n] = s;
    }
    __syncthreads();
    float vsum = 0.f, vlast = 0.f;
    for (int iter = 0; iter < 3; ++iter) {
        float mx = -1e30f;
        for (int i = 0; i < 72; ++i) mx = fmaxf(mx, uhl[e][chunk * 72 + i] * vsum);
        red[e][chunk] = mx;
        __syncthreads();
        float M = -1e30f;
#pragma unroll
        for (int k = 0; k < 16; ++k) M = fmaxf(M, red[e][k]);
        __syncthreads();
        float pe = 0.f, se = 0.f;
        for (int i = 0; i < 72; ++i) {
            float uv = uhl[e][chunk * 72 + i];
            float E = __expf(uv * vsum - M);
            pe += E;
            se += E * uv;
        }
        red[e][chunk] = pe;
        __syncthreads();
        float P = 0.f;
#pragma unroll
        for (int k = 0; k < 16; ++k) P += red[e][k];
        __syncthreads();
        red[e][chunk] = se;
        __syncthreads();
        float S = 0.f;
#pragma unroll
        for (int k = 0; k < 16; ++k) S += red[e][k];
        float sval = S / P;
        if (chunk == 0) sE[e] = sval;
        __syncthreads();
        float nrm = 0.f;
#pragma unroll
        for (int k = 0; k < 16; ++k) nrm += sE[k] * sE[k];
        float sc = nrm / ((nrm + 1.f) * (sqrtf(nrm) + EPS));
        vlast = sval * sc;
        vsum += vlast;
        __syncthreads();
    }
    if (chunk == 0) v[(b * 10 + c) * 16 + e] = vlast;
}

// -------------- logits = softmax over c of ||v|| ---------------------------------------
__global__ __launch_bounds__(256) void logits_k(const float* __restrict__ v,
                                                float* __restrict__ out) {
    int b = threadIdx.x;
    float nr[10];
#pragma unroll
    for (int c = 0; c < 10; ++c) {
        float s2 = 0.f;
#pragma unroll
        for (int e = 0; e < 16; ++e) {
            float xv = v[(b * 10 + c) * 16 + e];
            s2 += xv * xv;
        }
        nr[c] = sqrtf(s2);
    }
    float mx = nr[0];
#pragma unroll
    for (int c = 1; c < 10; ++c) mx = fmaxf(mx, nr[c]);
    float ex[10], sm = 0.f;
#pragma unroll
    for (int c = 0; c < 10; ++c) {
        ex[c] = __expf(nr[c] - mx);
        sm += ex[c];
    }
#pragma unroll
    for (int c = 0; c < 10; ++c) out[b * 10 + c] = ex[c] / sm;
}

// -------------- fc1: picks the 16 columns selected by y ------------------------------
__global__ __launch_bounds__(256) void fc1_k(const float* __restrict__ v,
                                             const int* __restrict__ y,
                                             const float* __restrict__ w1,
                                             const float* __restrict__ b1,
                                             float* __restrict__ h1) {
    int b = blockIdx.x, t = threadIdx.x;
    __shared__ float vs[16];
    int cls = y[b];
    if (t < 16) vs[t] = v[(b * 10 + cls) * 16 + t];
    __syncthreads();
    for (int j = t; j < 512; j += 256) {
        float a = b1[j];
#pragma unroll
        for (int d = 0; d < 16; ++d) a += vs[d] * w1[(cls * 16 + d) * 512 + j];
        h1[b * 512 + j] = fmaxf(a, 0.f);
    }
}

// -------------- generic fc: C[256,N] = (relu?)(A[256,K] @ W[K,N] + bias) ---------------
__global__ __launch_bounds__(256) void fc_k(const float* __restrict__ A,
                                            const float* __restrict__ Wt,
                                            const float* __restrict__ bias,
                                            float* __restrict__ C,
                                            int K, int N, int relu) {
    __shared__ float al[16 * 1024];
    int t = threadIdx.x;
    int j = blockIdx.x * 256 + t;
    int r0 = blockIdx.y * 16;
    for (int idx = t; idx < 16 * K; idx += 256) {
        int r = idx / K, kk = idx - r * K;
        al[r * K + kk] = A[(r0 + r) * K + kk];
    }
    __syncthreads();
    if (j < N) {
        float bj = bias[j];
        float acc[16];
#pragma unroll
        for (int i = 0; i < 16; ++i) acc[i] = bj;
        for (int k = 0; k < K; ++k) {
            float w = Wt[(long)k * N + j];
#pragma unroll
            for (int i = 0; i < 16; ++i) acc[i] += al[i * K + k] * w;
        }
#pragma unroll
        for (int i = 0; i < 16; ++i) {
            float o = acc[i];
            if (relu) o = fmaxf(o, 0.f);
            C[(r0 + i) * N + j] = o;
        }
    }
}

extern "C" void kernel_launch(void* const* d_in, const int* in_sizes, int n_in,
                              void* d_out, int out_size, void* d_ws, size_t ws_size,
                              hipStream_t stream) {
    (void)in_sizes; (void)n_in; (void)out_size; (void)ws_size;
    const float* x       = (const float*)d_in[0];
    const int*   y       = (const int*)d_in[1];
    const float* conv1_w = (const float*)d_in[2];
    const float* conv1_b = (const float*)d_in[3];
    const float* prim_w  = (const float*)d_in[4];
    const float* prim_b  = (const float*)d_in[5];
    const float* route_W = (const float*)d_in[6];
    const float* dec_w1  = (const float*)d_in[7];
    const float* dec_b1  = (const float*)d_in[8];
    const float* dec_w2  = (const float*)d_in[9];
    const float* dec_b2  = (const float*)d_in[10];
    const float* dec_w3  = (const float*)d_in[11];
    const float* dec_b3  = (const float*)d_in[12];
    float* out = (float*)d_out;

    float* ws  = (float*)d_ws;
    float* Cp  = ws;                  // 4 * 2359296 f32 (K-split partials)
    float* u   = Cp + 9437184;        // 2359296
    float* wt1 = u + 2359296;         // 20736
    float* v   = wt1 + 20736;         // 40960
    float* h1  = v + 40960;           // 131072
    float* h2  = h1 + 131072;         // 262144
    __half* hh = (__half*)(h2 + 262144);   // 26214400 halfs
    __half* w2 = hh + 26214400;            // 5308416 halfs

    hipLaunchKernelGGL(transpose_k, dim3(2, 4), dim3(256), 0, stream, conv1_w, wt1, 256, 81);
    hipLaunchKernelGGL(wprep_k, dim3(256, 2), dim3(256), 0, stream, prim_w, w2);
    hipLaunchKernelGGL(conv1_k, dim3(256, 2), dim3(256), 0, stream, x, wt1, conv1_b, hh);
    hipLaunchKernelGGL(primgemm_k, dim3(144, 4), dim3(256), 0, stream, hh, w2, Cp);
    hipLaunchKernelGGL(squashp_k, dim3(256), dim3(256), 0, stream, Cp, prim_b, u);
    hipLaunchKernelGGL(route_k, dim3(2560), dim3(256), 0, stream, u, route_W, v);
    hipLaunchKernelGGL(logits_k, dim3(1), dim3(256), 0, stream, v, out);
    hipLaunchKernelGGL(fc1_k, dim3(256), dim3(256), 0, stream, v, y, dec_w1, dec_b1, h1);
    hipLaunchKernelGGL(fc_k, dim3(4, 16), dim3(256), 0, stream, h1, dec_w2, dec_b2, h2, 512, 1024, 1);
    hipLaunchKernelGGL(fc_k, dim3(4, 16), dim3(256), 0, stream, h2, dec_w3, dec_b3, out + 2560, 1024, 784, 0);
}

// Round 4
// 616.247 us; speedup vs baseline: 11.0548x; 1.2340x over previous
//
#include <hip/hip_runtime.h>
#include <hip/hip_fp16.h>
#include <math.h>

#define EPS 1e-8f
#define AS1 __attribute__((address_space(1)))
#define AS3 __attribute__((address_space(3)))

typedef _Float16 f16x8 __attribute__((ext_vector_type(8)));
typedef float f32x4 __attribute__((ext_vector_type(4)));

// ---------------- generic [R][C] -> [C][R] transpose (64x64 LDS tiles) ----------------
__global__ __launch_bounds__(256) void transpose_k(const float* __restrict__ in,
                                                   float* __restrict__ out, int R, int C) {
    __shared__ float tile[64][65];
    int tx = threadIdx.x & 63, ty = threadIdx.x >> 6;
    int c0 = blockIdx.x * 64, r0 = blockIdx.y * 64;
#pragma unroll
    for (int i = 0; i < 16; ++i) {
        int r = r0 + ty + i * 4, c = c0 + tx;
        if (r < R && c < C) tile[ty + i * 4][tx] = in[(long)r * C + c];
    }
    __syncthreads();
#pragma unroll
    for (int i = 0; i < 16; ++i) {
        int r = c0 + ty + i * 4, c = r0 + tx;
        if (r < C && c < R) out[(long)r * R + c] = tile[tx][ty + i * 4];
    }
}

// -------- weight prep: prim_w [co][ci][81] f32 -> w2 [co][tap][ci] fp16 ----------------
__global__ __launch_bounds__(256) void wprep_k(const float* __restrict__ prim_w,
                                               __half* __restrict__ w2) {
    __shared__ float pl[128 * 81];
    int t = threadIdx.x, co = blockIdx.x, cih = blockIdx.y;
    for (int i = t; i < 10368; i += 256) pl[i] = prim_w[co * 20736 + cih * 10368 + i];
    __syncthreads();
    for (int o = t; o < 10368; o += 256) {  // o = tap*128 + cil
        int tap = o >> 7, cil = o & 127;
        w2[(long)co * 20736 + tap * 256 + cih * 128 + cil] = __float2half(pl[cil * 81 + tap]);
    }
}

// ---------------- conv1 9x9 stride1 + bias + relu -> hh [b][400 pix][256 ci] fp16 -------
// grid (256 images, 4 = chalf*2 + pixhalf)
__global__ __launch_bounds__(256) void conv1_k(const float* __restrict__ x,
                                               const float* __restrict__ wt1,  // [81][256]
                                               const float* __restrict__ bias,
                                               __half* __restrict__ hh) {
    __shared__ float img[784];
    __shared__ float wl2[81 * 128];
    int t = threadIdx.x, b = blockIdx.x;
    int chalf = blockIdx.y >> 1, ph = blockIdx.y & 1;
    for (int i = t; i < 784; i += 256) img[i] = x[b * 784 + i];
    for (int i = t; i < 81 * 128; i += 256) {
        int tap = i >> 7, j = i & 127;
        wl2[i] = wt1[tap * 256 + chalf * 128 + j];
    }
    __syncthreads();
    int lane = t & 63, grp = t >> 6;
    int col = lane * 2;
    float2 cb = *(const float2*)&bias[chalf * 128 + col];
    int ow0 = ph * 10;
    for (int oh = grp * 5; oh < grp * 5 + 5; ++oh) {
        float acc0[10], acc1[10];
#pragma unroll
        for (int p = 0; p < 10; ++p) { acc0[p] = 0.f; acc1[p] = 0.f; }
        for (int kh = 0; kh < 9; ++kh) {
            for (int kw = 0; kw < 9; ++kw) {
                float2 w2v = *(const float2*)&wl2[(kh * 9 + kw) * 128 + col];
                const float* irow = &img[(oh + kh) * 28 + ow0 + kw];
#pragma unroll
                for (int p = 0; p < 10; ++p) {
                    float iv = irow[p];
                    acc0[p] += iv * w2v.x;
                    acc1[p] += iv * w2v.y;
                }
            }
        }
#pragma unroll
        for (int p = 0; p < 10; ++p) {
            int pix = oh * 20 + ow0 + p;
            __half2 hv;
            hv.x = __float2half(fmaxf(acc0[p] + cb.x, 0.f));
            hv.y = __float2half(fmaxf(acc1[p] + cb.y, 0.f));
            *(__half2*)&hh[((long)b * 400 + pix) * 256 + chalf * 128 + col] = hv;
        }
    }
}

// ---------------- primary-caps implicit GEMM v3 ----------------------------------------
// ci-based K-split: slice ks owns ci [ks*64, ks*64+64); 81 tap-steps of BK=64.
// Block: 128 m x 128 co, 4 waves, wave tile 64x64 (4 mf x 4 nf, acc 64 VGPR).
// BOTH A (im2col gather) and W staged in LDS via global_load_lds,
// linear LDS dest + inverse-XOR-swizzled per-lane global source, XOR-swizzled reads.
// grid flat 576 = mt*8 + nb*4 + ks  (XCD x sees one (nb,ks): W slice L2-resident).
__global__ __launch_bounds__(256) void primgemm_k(const __half* __restrict__ hh,
                                                  const __half* __restrict__ w2,
                                                  float* __restrict__ Cpart) {
    __shared__ __align__(16) char lds[2][32768];  // [buf][ W 16K | A 16K ]
    const int t = threadIdx.x;
    const int lane = t & 63, w = t >> 6;
    const int l15 = lane & 15, kl = lane >> 4;
    const int sw = l15 & 7;

    const int bx = blockIdx.x;
    const int mt = bx >> 3, nb = (bx >> 2) & 1, ks = bx & 3;
    const int mr = w >> 1, nc = w & 1;

    // staging geometry: 4 W calls + 4 A calls; call q writes rows q*32+w*8+(lane>>3)
    long wsrc[4], asrc[4];
    int dstW[4];
#pragma unroll
    for (int q = 0; q < 4; ++q) {
        int row = q * 32 + w * 8 + (lane >> 3);
        int lc = (lane & 7) ^ (row & 7);
        dstW[q] = q * 4096 + w * 1024;
        wsrc[q] = (long)(nb * 128 + row) * 20736 + ks * 64 + lc * 8;
        int m = mt * 128 + row;
        int bi = m / 36, pos = m - bi * 36;
        int oy = pos / 6, ox = pos - oy * 6;
        asrc[q] = ((long)bi * 400 + oy * 40 + ox * 2) * 256 + ks * 64 + lc * 8;
    }

    f32x4 acc[4][4];
#pragma unroll
    for (int i = 0; i < 4; ++i)
#pragma unroll
        for (int j = 0; j < 4; ++j) acc[i][j] = (f32x4){0.f, 0.f, 0.f, 0.f};

    auto stage = [&](int bufi, int tap) {
        int kh = tap / 9, kw = tap - kh * 9;
        int woff = tap * 256;
        int aoff = (kh * 20 + kw) * 256;
#pragma unroll
        for (int q = 0; q < 4; ++q)
            __builtin_amdgcn_global_load_lds((const AS1 void*)(w2 + wsrc[q] + woff),
                                             (AS3 void*)(&lds[bufi][dstW[q]]), 16, 0, 0);
#pragma unroll
        for (int q = 0; q < 4; ++q)
            __builtin_amdgcn_global_load_lds((const AS1 void*)(hh + asrc[q] + aoff),
                                             (AS3 void*)(&lds[bufi][16384 + dstW[q]]), 16, 0, 0);
    };

    // per-lane read offsets (lane-const)
    int wrowb[4], arowb[4], rdoff[2];
#pragma unroll
    for (int f = 0; f < 4; ++f) {
        wrowb[f] = (nc * 64 + f * 16 + l15) * 128;
        arowb[f] = 16384 + (mr * 64 + f * 16 + l15) * 128;
    }
#pragma unroll
    for (int kc = 0; kc < 2; ++kc) rdoff[kc] = ((kc * 4 + kl) ^ sw) << 4;

    stage(0, 0);
    __syncthreads();
    int buf = 0;
    for (int s = 0; s < 81; ++s) {
        if (s < 80) stage(buf ^ 1, s + 1);
        const char* B = lds[buf];
#pragma unroll
        for (int kc = 0; kc < 2; ++kc) {
            f16x8 wf[4], af[4];
#pragma unroll
            for (int nf = 0; nf < 4; ++nf) wf[nf] = *(const f16x8*)(B + wrowb[nf] + rdoff[kc]);
#pragma unroll
            for (int mf = 0; mf < 4; ++mf) af[mf] = *(const f16x8*)(B + arowb[mf] + rdoff[kc]);
#pragma unroll
            for (int mf = 0; mf < 4; ++mf)
#pragma unroll
                for (int nf = 0; nf < 4; ++nf)
                    acc[mf][nf] = __builtin_amdgcn_mfma_f32_16x16x32_f16(wf[nf], af[mf],
                                                                         acc[mf][nf], 0, 0, 0);
        }
        __syncthreads();
        buf ^= 1;
    }

    // epilogue: D col = m (lane&15), row = co ((lane>>4)*4 + j)
    float* Cp = Cpart + (long)ks * 2359296;
#pragma unroll
    for (int mf = 0; mf < 4; ++mf)
#pragma unroll
        for (int nf = 0; nf < 4; ++nf) {
            int m = mt * 128 + mr * 64 + mf * 16 + l15;
            int co = nb * 128 + nc * 64 + nf * 16 + kl * 4;
            *(f32x4*)(Cp + (long)m * 256 + co) = acc[mf][nf];
        }
}

// -------------- sum 4 K-partials + bias + capsule regroup + squash -> u ----------------
__global__ __launch_bounds__(256) void squashp_k(const float* __restrict__ Cpart,
                                                 const float* __restrict__ bias,
                                                 float* __restrict__ u) {
    __shared__ float sm[9216];  // [pos][co]
    __shared__ float bs[256];
    int t = threadIdx.x, b = blockIdx.x;
    bs[t] = bias[t];
    for (int i = t; i < 9216; i += 256) {
        float s = 0.f;
#pragma unroll
        for (int ks = 0; ks < 4; ++ks) s += Cpart[(long)ks * 2359296 + (long)b * 9216 + i];
        sm[i] = s;
    }
    __syncthreads();
    for (int cap = t; cap < 1152; cap += 256) {
        float xs[8], sn = 0.f;
#pragma unroll
        for (int d = 0; d < 8; ++d) {
            int f = cap * 8 + d;
            int co = f / 36, pos = f - co * 36;
            float vv = sm[pos * 256 + co] + bs[co];
            xs[d] = vv;
            sn += vv * vv;
        }
        float sc = sn / ((sn + 1.f) * (sqrtf(sn) + EPS));
#pragma unroll
        for (int d = 0; d < 8; ++d) u[(long)b * 9216 + cap * 8 + d] = xs[d] * sc;
    }
}

// -------------- u_hat + 3-iter dynamic routing, one block per (c,b) --------------------
__global__ __launch_bounds__(256) void route_k(const float* __restrict__ u,
                                               const float* __restrict__ W,  // [10][1152][8][16]
                                               float* __restrict__ v) {
    __shared__ float uhl[16][1153];
    __shared__ float red[16][16];
    __shared__ float sE[16];
    int t = threadIdx.x;
    int c = blockIdx.x >> 8, b = blockIdx.x & 255;
    int e = t & 15, chunk = t >> 4;
    const float* Wc = W + c * 147456;
    const float* ub = u + b * 9216;
    for (int i = 0; i < 72; ++i) {
        int n = chunk * 72 + i;
        const float* un = ub + n * 8;
        const float* wn = Wc + n * 128 + e;
        float s = 0.f;
#pragma unroll
        for (int d = 0; d < 8; ++d) s += un[d] * wn[d * 16];
        uhl[e][n] = s;
    }
    __syncthreads();
    float vsum = 0.f, vlast = 0.f;
    for (int iter = 0; iter < 3; ++iter) {
        float mx = -1e30f;
        for (int i = 0; i < 72; ++i) mx = fmaxf(mx, uhl[e][chunk * 72 + i] * vsum);
        red[e][chunk] = mx;
        __syncthreads();
        float M = -1e30f;
#pragma unroll
        for (int k = 0; k < 16; ++k) M = fmaxf(M, red[e][k]);
        __syncthreads();
        float pe = 0.f, se = 0.f;
        for (int i = 0; i < 72; ++i) {
            float uv = uhl[e][chunk * 72 + i];
            float E = __expf(uv * vsum - M);
            pe += E;
            se += E * uv;
        }
        red[e][chunk] = pe;
        __syncthreads();
        float P = 0.f;
#pragma unroll
        for (int k = 0; k < 16; ++k) P += red[e][k];
        __syncthreads();
        red[e][chunk] = se;
        __syncthreads();
        float S = 0.f;
#pragma unroll
        for (int k = 0; k < 16; ++k) S += red[e][k];
        float sval = S / P;
        if (chunk == 0) sE[e] = sval;
        __syncthreads();
        float nrm = 0.f;
#pragma unroll
        for (int k = 0; k < 16; ++k) nrm += sE[k] * sE[k];
        float sc = nrm / ((nrm + 1.f) * (sqrtf(nrm) + EPS));
        vlast = sval * sc;
        vsum += vlast;
        __syncthreads();
    }
    if (chunk == 0) v[(b * 10 + c) * 16 + e] = vlast;
}

// -------------- logits = softmax over c of ||v|| ---------------------------------------
__global__ __launch_bounds__(256) void logits_k(const float* __restrict__ v,
                                                float* __restrict__ out) {
    int b = threadIdx.x;
    float nr[10];
#pragma unroll
    for (int c = 0; c < 10; ++c) {
        float s2 = 0.f;
#pragma unroll
        for (int e = 0; e < 16; ++e) {
            float xv = v[(b * 10 + c) * 16 + e];
            s2 += xv * xv;
        }
        nr[c] = sqrtf(s2);
    }
    float mx = nr[0];
#pragma unroll
    for (int c = 1; c < 10; ++c) mx = fmaxf(mx, nr[c]);
    float ex[10], sm = 0.f;
#pragma unroll
    for (int c = 0; c < 10; ++c) {
        ex[c] = __expf(nr[c] - mx);
        sm += ex[c];
    }
#pragma unroll
    for (int c = 0; c < 10; ++c) out[b * 10 + c] = ex[c] / sm;
}

// -------------- fc1: picks the 16 columns selected by y ------------------------------
__global__ __launch_bounds__(256) void fc1_k(const float* __restrict__ v,
                                             const int* __restrict__ y,
                                             const float* __restrict__ w1,
                                             const float* __restrict__ b1,
                                             float* __restrict__ h1) {
    int b = blockIdx.x, t = threadIdx.x;
    __shared__ float vs[16];
    int cls = y[b];
    if (t < 16) vs[t] = v[(b * 10 + cls) * 16 + t];
    __syncthreads();
    for (int j = t; j < 512; j += 256) {
        float a = b1[j];
#pragma unroll
        for (int d = 0; d < 16; ++d) a += vs[d] * w1[(cls * 16 + d) * 512 + j];
        h1[b * 512 + j] = fmaxf(a, 0.f);
    }
}

// -------------- generic fc: C[256,N] = (relu?)(A[256,K] @ W[K,N] + bias) ---------------
// grid (ceil(N/256), 32); 8 rows of A staged in LDS per block.
__global__ __launch_bounds__(256) void fc_k(const float* __restrict__ A,
                                            const float* __restrict__ Wt,
                                            const float* __restrict__ bias,
                                            float* __restrict__ C,
                                            int K, int N, int relu) {
    __shared__ float al[8 * 1024];
    int t = threadIdx.x;
    int j = blockIdx.x * 256 + t;
    int r0 = blockIdx.y * 8;
    for (int idx = t; idx < 8 * K; idx += 256) {
        int r = idx / K, kk = idx - r * K;
        al[r * K + kk] = A[(r0 + r) * K + kk];
    }
    __syncthreads();
    if (j < N) {
        float bj = bias[j];
        float acc[8];
#pragma unroll
        for (int i = 0; i < 8; ++i) acc[i] = bj;
        for (int k = 0; k < K; ++k) {
            float w = Wt[(long)k * N + j];
#pragma unroll
            for (int i = 0; i < 8; ++i) acc[i] += al[i * K + k] * w;
        }
#pragma unroll
        for (int i = 0; i < 8; ++i) {
            float o = acc[i];
            if (relu) o = fmaxf(o, 0.f);
            C[(r0 + i) * N + j] = o;
        }
    }
}

extern "C" void kernel_launch(void* const* d_in, const int* in_sizes, int n_in,
                              void* d_out, int out_size, void* d_ws, size_t ws_size,
                              hipStream_t stream) {
    (void)in_sizes; (void)n_in; (void)out_size; (void)ws_size;
    const float* x       = (const float*)d_in[0];
    const int*   y       = (const int*)d_in[1];
    const float* conv1_w = (const float*)d_in[2];
    const float* conv1_b = (const float*)d_in[3];
    const float* prim_w  = (const float*)d_in[4];
    const float* prim_b  = (const float*)d_in[5];
    const float* route_W = (const float*)d_in[6];
    const float* dec_w1  = (const float*)d_in[7];
    const float* dec_b1  = (const float*)d_in[8];
    const float* dec_w2  = (const float*)d_in[9];
    const float* dec_b2  = (const float*)d_in[10];
    const float* dec_w3  = (const float*)d_in[11];
    const float* dec_b3  = (const float*)d_in[12];
    float* out = (float*)d_out;

    float* ws  = (float*)d_ws;
    float* Cp  = ws;                  // 4 * 2359296 f32 (ci-split partials)
    float* u   = Cp + 9437184;        // 2359296
    float* wt1 = u + 2359296;         // 20736
    float* v   = wt1 + 20736;         // 40960
    float* h1  = v + 40960;           // 131072
    float* h2  = h1 + 131072;         // 262144
    __half* hh = (__half*)(h2 + 262144);   // 26214400 halfs
    __half* w2 = hh + 26214400;            // 5308416 halfs

    hipLaunchKernelGGL(transpose_k, dim3(2, 4), dim3(256), 0, stream, conv1_w, wt1, 256, 81);
    hipLaunchKernelGGL(wprep_k, dim3(256, 2), dim3(256), 0, stream, prim_w, w2);
    hipLaunchKernelGGL(conv1_k, dim3(256, 4), dim3(256), 0, stream, x, wt1, conv1_b, hh);
    hipLaunchKernelGGL(primgemm_k, dim3(576), dim3(256), 0, stream, hh, w2, Cp);
    hipLaunchKernelGGL(squashp_k, dim3(256), dim3(256), 0, stream, Cp, prim_b, u);
    hipLaunchKernelGGL(route_k, dim3(2560), dim3(256), 0, stream, u, route_W, v);
    hipLaunchKernelGGL(logits_k, dim3(1), dim3(256), 0, stream, v, out);
    hipLaunchKernelGGL(fc1_k, dim3(256), dim3(256), 0, stream, v, y, dec_w1, dec_b1, h1);
    hipLaunchKernelGGL(fc_k, dim3(4, 32), dim3(256), 0, stream, h1, dec_w2, dec_b2, h2, 512, 1024, 1);
    hipLaunchKernelGGL(fc_k, dim3(4, 32), dim3(256), 0, stream, h2, dec_w3, dec_b3, out + 2560, 1024, 784, 0);
}